// Round 1
// baseline (1673.039 us; speedup 1.0000x reference)
//
#include <hip/hip_runtime.h>
#include <hip/hip_bf16.h>

// Problem constants (from reference config)
#define CIN 256
#define COUT 256
#define HW 56
#define BATCH 8
#define L_SPATIAL 3136            // 56*56
#define K_TOTAL 2304              // CIN*3*3
#define NT 36                     // K_TOTAL / 64 chunks
#define KSTRIDE 2312              // bf16 elems per m-row in LDS (+8 pad: breaks 16-way bank conflict)
#define LDS_BYTES (16 * KSTRIDE * 2)   // 73,984 B -> 2 WGs/CU
#define QMAXF 127.0f
#define QMINF -128.0f

typedef short bf16x8 __attribute__((ext_vector_type(8)));
typedef float f32x4 __attribute__((ext_vector_type(4)));

// ---- prep: Bsign[c][k] = sign(w) as bf16 (B^T layout = MFMA B-frag order), scale[c] = mean|w| ----
__global__ __launch_bounds__(256) void prep_kernel(
    const float* __restrict__ w, unsigned short* __restrict__ bsign,
    float* __restrict__ scale) {
  const int c = blockIdx.x;
  const int t = threadIdx.x;
  const float* row = w + (size_t)c * K_TOTAL;
  unsigned short* out = bsign + (size_t)c * K_TOTAL;
  float acc = 0.0f;
#pragma unroll
  for (int j = 0; j < 9; ++j) {
    const int k = t + 256 * j;
    const float v = row[k];
    acc += __builtin_fabsf(v);
    out[k] = (v > 0.0f) ? (unsigned short)0x3F80
           : ((v < 0.0f) ? (unsigned short)0xBF80 : (unsigned short)0);
  }
#pragma unroll
  for (int o = 32; o > 0; o >>= 1) acc += __shfl_down(acc, o, 64);
  __shared__ float red[4];
  if ((t & 63) == 0) red[t >> 6] = acc;
  __syncthreads();
  if (t == 0) scale[c] = (red[0] + red[1] + red[2] + red[3]) * (1.0f / 2304.0f);
}

// ---- main: per WG = 16 m-rows x 256 cout, 36 psum chunks + saturating scan ----
__global__ __launch_bounds__(256, 2) void satconv_kernel(
    const float* __restrict__ x, const unsigned short* __restrict__ bsign,
    const float* __restrict__ scale, float* __restrict__ y_out,
    float* __restrict__ psum_out) {
  extern __shared__ unsigned short Atile[];   // [16][KSTRIDE] bf16, im2col order
  const int tid = threadIdx.x;
  const int m0 = blockIdx.x << 4;

  // ---------- build A tile: lanes 0-15 = consecutive m (= consecutive ow) for coalesced x reads ----------
  {
    const int ml = tid & 15;
    const int grp = tid >> 4;                 // 0..15
    const int m = m0 + ml;
    const int b = m / L_SPATIAL;
    const int l = m - b * L_SPATIAL;
    const int oh = l / HW;
    const int ow = l - oh * HW;
    const float* xb = x + (size_t)b * (CIN * L_SPATIAL);
    unsigned short* arow = Atile + ml * KSTRIDE;
    for (int r = grp; r < 768; r += 16) {     // r = ci*3 + kh
      const int ci = r / 3;
      const int kh = r - ci * 3;
      const int h = oh + kh - 1;
      const bool hv = ((unsigned)h < (unsigned)HW);
      const float* xr = xb + (ci * HW + h) * HW;
      const int kb = ci * 9 + kh * 3;
#pragma unroll
      for (int kw = 0; kw < 3; ++kw) {
        const int wv = ow + kw - 1;
        float v = 0.0f;
        if (hv && ((unsigned)wv < (unsigned)HW)) v = xr[wv];
        __hip_bfloat16 bv = __float2bfloat16(v);
        arow[kb + kw] = *reinterpret_cast<unsigned short*>(&bv);
      }
    }
  }
  __syncthreads();

  const int lane = tid & 63;
  const int wave = tid >> 6;
  const int cl = lane & 15;                   // MFMA col (c) / A row (m)
  const int q = lane >> 4;                    // quad
  const int c0 = wave << 6;                   // 64 couts per wave

  const unsigned short* aptr = Atile + cl * KSTRIDE + q * 8;

  for (int s = 0; s < 4; ++s) {               // 4 c-subtiles of 16
    const int c = c0 + (s << 4) + cl;
    const unsigned short* bptr = bsign + (size_t)c * K_TOTAL + q * 8;
    f32x4 ps[NT];
    f32x4 sacc = {0.0f, 0.0f, 0.0f, 0.0f};
    const f32x4 zero = {0.0f, 0.0f, 0.0f, 0.0f};
#pragma unroll
    for (int n = 0; n < NT; ++n) {
      bf16x8 a0 = *reinterpret_cast<const bf16x8*>(aptr + n * 64);
      bf16x8 a1 = *reinterpret_cast<const bf16x8*>(aptr + n * 64 + 32);
      bf16x8 b0 = *reinterpret_cast<const bf16x8*>(bptr + n * 64);
      bf16x8 b1 = *reinterpret_cast<const bf16x8*>(bptr + n * 64 + 32);
      f32x4 acc = __builtin_amdgcn_mfma_f32_16x16x32_bf16(a0, b0, zero, 0, 0, 0);
      acc = __builtin_amdgcn_mfma_f32_16x16x32_bf16(a1, b1, acc, 0, 0, 0);
      ps[n] = acc;
      if (n == 0) {
        sacc = acc;                           // scan carry starts UNCLIPPED (matches ref)
      } else {
#pragma unroll
        for (int e = 0; e < 4; ++e) {
          const float t = sacc[e] + acc[e];
          sacc[e] = __builtin_amdgcn_fmed3f(t, QMINF, QMAXF);
        }
      }
    }
    // ---- psum store: per output row, all 36 n's as 9 contiguous dwordx4 (full-line combining) ----
    const size_t rowbase = ((size_t)(m0 + (q << 2)) * COUT + c) * NT;
#pragma unroll
    for (int rg = 0; rg < 4; ++rg) {
      float* prow = psum_out + rowbase + (size_t)rg * (COUT * NT);
#pragma unroll
      for (int g = 0; g < 9; ++g) {
        f32x4 v = {ps[4 * g + 0][rg], ps[4 * g + 1][rg],
                   ps[4 * g + 2][rg], ps[4 * g + 3][rg]};
        *reinterpret_cast<f32x4*>(prow + 4 * g) = v;
      }
    }
    // ---- y store: y[b][c][l] = clipped_sum * scale[c] ----
    const float sc = scale[c];
#pragma unroll
    for (int rg = 0; rg < 4; ++rg) {
      const int row = m0 + (q << 2) + rg;
      const int b = row / L_SPATIAL;
      const int l = row - b * L_SPATIAL;
      y_out[((size_t)b * COUT + c) * L_SPATIAL + l] = sacc[rg] * sc;
    }
  }
}

extern "C" void kernel_launch(void* const* d_in, const int* in_sizes, int n_in,
                              void* d_out, int out_size, void* d_ws, size_t ws_size,
                              hipStream_t stream) {
  const float* x = (const float*)d_in[0];
  const float* w = (const float*)d_in[1];
  float* y = (float*)d_out;
  float* psum = y + (size_t)BATCH * COUT * L_SPATIAL;            // y is 6,422,528 floats
  unsigned short* bsign = (unsigned short*)d_ws;                 // 256*2304*2 = 1,179,648 B
  float* scale = (float*)((char*)d_ws + (size_t)COUT * K_TOTAL * 2);

  prep_kernel<<<COUT, 256, 0, stream>>>(w, bsign, scale);

  hipFuncSetAttribute(reinterpret_cast<const void*>(satconv_kernel),
                      hipFuncAttributeMaxDynamicSharedMemorySize, LDS_BYTES);
  satconv_kernel<<<(BATCH * L_SPATIAL) / 16, 256, LDS_BYTES, stream>>>(
      x, bsign, scale, y, psum);
}

// Round 2
// 1259.335 us; speedup vs baseline: 1.3285x; 1.3285x over previous
//
#include <hip/hip_runtime.h>
#include <hip/hip_bf16.h>

// Problem constants (from reference config)
#define CIN 256
#define COUT 256
#define HW 56
#define BATCH 8
#define L_SPATIAL 3136            // 56*56
#define K_TOTAL 2304              // CIN*3*3
#define NT 36                     // K_TOTAL / 64 chunks
#define KSTRIDE 2312              // bf16 elems per m-row in LDS (+8 pad)
#define ATILE_BYTES (16 * KSTRIDE * 2)       // 73,984 B
#define STAGE_FLOATS 2304                    // per-wave staging: 4m x 16c x 36n
#define LDS_BYTES (ATILE_BYTES + 8 * STAGE_FLOATS * 4)  // 147,712 B -> 1 WG/CU, 8 waves
#define QMAXF 127.0f
#define QMINF -128.0f

typedef short bf16x8 __attribute__((ext_vector_type(8)));
typedef float f32x4 __attribute__((ext_vector_type(4)));

// ---- prep: Bsign[c][k] = sign(w) as bf16 (B^T layout = MFMA B-frag order), scale[c] = mean|w| ----
__global__ __launch_bounds__(256) void prep_kernel(
    const float* __restrict__ w, unsigned short* __restrict__ bsign,
    float* __restrict__ scale) {
  const int c = blockIdx.x;
  const int t = threadIdx.x;
  const float* row = w + (size_t)c * K_TOTAL;
  unsigned short* out = bsign + (size_t)c * K_TOTAL;
  float acc = 0.0f;
#pragma unroll
  for (int j = 0; j < 9; ++j) {
    const int k = t + 256 * j;
    const float v = row[k];
    acc += __builtin_fabsf(v);
    out[k] = (v > 0.0f) ? (unsigned short)0x3F80
           : ((v < 0.0f) ? (unsigned short)0xBF80 : (unsigned short)0);
  }
#pragma unroll
  for (int o = 32; o > 0; o >>= 1) acc += __shfl_down(acc, o, 64);
  __shared__ float red[4];
  if ((t & 63) == 0) red[t >> 6] = acc;
  __syncthreads();
  if (t == 0) scale[c] = (red[0] + red[1] + red[2] + red[3]) * (1.0f / 2304.0f);
}

// ---- main: per WG = 16 m-rows x 256 cout (8 waves x 32c), LDS-staged coalesced output ----
__global__ __launch_bounds__(512, 1) void satconv_kernel(
    const float* __restrict__ x, const unsigned short* __restrict__ bsign,
    const float* __restrict__ scale, float* __restrict__ y_out,
    float* __restrict__ psum_out) {
  extern __shared__ char smem[];
  unsigned short* Atile = (unsigned short*)smem;               // [16][KSTRIDE] bf16
  float* stage_base = (float*)(smem + ATILE_BYTES);            // [8 waves][2304] f32

  const int tid = threadIdx.x;
  const int m0 = blockIdx.x << 4;

  // ---------- build A tile: lanes 0-15 = consecutive m (= consecutive ow), coalesced x reads ----------
  {
    const int ml = tid & 15;
    const int grp = tid >> 4;                 // 0..31
    const int m = m0 + ml;
    const int b = m / L_SPATIAL;
    const int l = m - b * L_SPATIAL;
    const int oh = l / HW;
    const int ow = l - oh * HW;
    const float* xb = x + (size_t)b * (CIN * L_SPATIAL);
    unsigned short* arow = Atile + ml * KSTRIDE;
    for (int r = grp; r < 768; r += 32) {     // r = ci*3 + kh
      const int ci = r / 3;
      const int kh = r - ci * 3;
      const int h = oh + kh - 1;
      const bool hv = ((unsigned)h < (unsigned)HW);
      const float* xr = xb + (ci * HW + h) * HW;
      const int kb = ci * 9 + kh * 3;
#pragma unroll
      for (int kw = 0; kw < 3; ++kw) {
        const int wv = ow + kw - 1;
        float v = 0.0f;
        if (hv && ((unsigned)wv < (unsigned)HW)) v = xr[wv];
        __hip_bfloat16 bv = __float2bfloat16(v);
        arow[kb + kw] = *reinterpret_cast<unsigned short*>(&bv);
      }
    }
  }
  __syncthreads();

  const int lane = tid & 63;
  const int wave = tid >> 6;                  // 0..7
  const int cl = lane & 15;
  const int q = lane >> 4;
  const int c0 = wave << 5;                   // 32 couts per wave
  float* stage = stage_base + wave * STAGE_FLOATS;   // private -> no barriers (DS in-order per wave)

  const unsigned short* aptr = Atile + cl * KSTRIDE + q * 8;
  const int b_img = m0 / L_SPATIAL;           // WG never crosses batch boundary (3136 % 16 == 0)
  const int l0 = m0 - b_img * L_SPATIAL;

  for (int s = 0; s < 2; ++s) {               // 2 c-subtiles of 16 per wave
    const int csub0 = c0 + (s << 4);
    const int c = csub0 + cl;
    const unsigned short* bptr = bsign + (size_t)c * K_TOTAL + q * 8;
    f32x4 ps[NT];
    f32x4 sacc = {0.0f, 0.0f, 0.0f, 0.0f};
    const f32x4 zero = {0.0f, 0.0f, 0.0f, 0.0f};
#pragma unroll
    for (int n = 0; n < NT; ++n) {
      bf16x8 a0 = *reinterpret_cast<const bf16x8*>(aptr + n * 64);
      bf16x8 a1 = *reinterpret_cast<const bf16x8*>(aptr + n * 64 + 32);
      bf16x8 b0 = *reinterpret_cast<const bf16x8*>(bptr + n * 64);
      bf16x8 b1 = *reinterpret_cast<const bf16x8*>(bptr + n * 64 + 32);
      f32x4 acc = __builtin_amdgcn_mfma_f32_16x16x32_bf16(a0, b0, zero, 0, 0, 0);
      acc = __builtin_amdgcn_mfma_f32_16x16x32_bf16(a1, b1, acc, 0, 0, 0);
      ps[n] = acc;
      if (n == 0) {
        sacc = acc;                           // scan carry starts UNCLIPPED (matches ref)
      } else {
#pragma unroll
        for (int e = 0; e < 4; ++e) {
          const float t = sacc[e] + acc[e];
          sacc[e] = __builtin_amdgcn_fmed3f(t, QMINF, QMAXF);
        }
      }
    }

    // ---- psum: transpose via per-wave LDS staging, store as dense 1KB wave instructions ----
#pragma unroll
    for (int rg = 0; rg < 4; ++rg) {
      // write phase: [q][c][n] linear layout, 9 x ds_write_b128 per lane
#pragma unroll
      for (int g = 0; g < 9; ++g) {
        f32x4 v = {ps[4 * g + 0][rg], ps[4 * g + 1][rg],
                   ps[4 * g + 2][rg], ps[4 * g + 3][rg]};
        *reinterpret_cast<f32x4*>(stage + q * 576 + cl * 36 + 4 * g) = v;
      }
      // read phase: perfectly linear (lane*16B) -> fully coalesced global stores
#pragma unroll
      for (int it = 0; it < 9; ++it) {
        const int f = it * 256 + lane * 4;
        const int qq = f / 576;
        const int rem = f - qq * 576;
        const int ci = rem / 36;
        const int n0 = rem - ci * 36;
        f32x4 v = *reinterpret_cast<const f32x4*>(stage + f);
        const size_t goff =
            ((size_t)(m0 + (qq << 2) + rg) * COUT + (csub0 + ci)) * NT + n0;
        *reinterpret_cast<f32x4*>(psum_out + goff) = v;
      }
    }

    // ---- y: stage 16c x 16m block, store as full 64B lines ----
    {
      const float sc = scale[c];
      f32x4 yv;
#pragma unroll
      for (int e = 0; e < 4; ++e) yv[e] = sacc[e] * sc;
      *reinterpret_cast<f32x4*>(stage + cl * 16 + q * 4) = yv;   // [c][m'] layout
      const int ci = lane >> 2;
      const int mi = (lane & 3) << 2;
      f32x4 v = *reinterpret_cast<const f32x4*>(stage + lane * 4);
      *reinterpret_cast<f32x4*>(
          y_out + ((size_t)b_img * COUT + (csub0 + ci)) * L_SPATIAL + l0 + mi) = v;
    }
  }
}

extern "C" void kernel_launch(void* const* d_in, const int* in_sizes, int n_in,
                              void* d_out, int out_size, void* d_ws, size_t ws_size,
                              hipStream_t stream) {
  const float* x = (const float*)d_in[0];
  const float* w = (const float*)d_in[1];
  float* y = (float*)d_out;
  float* psum = y + (size_t)BATCH * COUT * L_SPATIAL;            // y is 6,422,528 floats
  unsigned short* bsign = (unsigned short*)d_ws;                 // 256*2304*2 = 1,179,648 B
  float* scale = (float*)((char*)d_ws + (size_t)COUT * K_TOTAL * 2);

  prep_kernel<<<COUT, 256, 0, stream>>>(w, bsign, scale);

  hipFuncSetAttribute(reinterpret_cast<const void*>(satconv_kernel),
                      hipFuncAttributeMaxDynamicSharedMemorySize, LDS_BYTES);
  satconv_kernel<<<(BATCH * L_SPATIAL) / 16, 512, LDS_BYTES, stream>>>(
      x, bsign, scale, y, psum);
}

// Round 3
// 1186.764 us; speedup vs baseline: 1.4097x; 1.0612x over previous
//
#include <hip/hip_runtime.h>
#include <hip/hip_bf16.h>

// Problem constants (from reference config)
#define CIN 256
#define COUT 256
#define HW 56
#define BATCH 8
#define L_SPATIAL 3136            // 56*56
#define K_TOTAL 2304              // CIN*3*3
#define NT 36                     // K_TOTAL / 64 chunks
#define KSTRIDE 2312              // bf16 elems per m-row in LDS (+8 pad)
#define ATILE_BYTES (16 * KSTRIDE * 2)       // 73,984 B
#define STAGE_FLOATS 2304                    // per-wave staging: 4m x 16c x 36n (one rg at a time)
#define LDS_BYTES (ATILE_BYTES + 8 * STAGE_FLOATS * 4)  // 147,712 B -> 1 WG/CU, 8 waves
#define TILES_PER_IMG 196                    // 3136/16 m-tiles per batch image
#define QMAXF 127.0f
#define QMINF -128.0f

typedef short bf16x8 __attribute__((ext_vector_type(8)));
typedef float f32x4 __attribute__((ext_vector_type(4)));

__device__ __forceinline__ void nt_store4(float* p, f32x4 v) {
  __builtin_nontemporal_store(v, reinterpret_cast<f32x4*>(p));
}

// ---- prep: Bsign[c][k] = sign(w) as bf16 (B^T layout = MFMA B-frag order), scale[c] = mean|w| ----
__global__ __launch_bounds__(256) void prep_kernel(
    const float* __restrict__ w, unsigned short* __restrict__ bsign,
    float* __restrict__ scale) {
  const int c = blockIdx.x;
  const int t = threadIdx.x;
  const float* row = w + (size_t)c * K_TOTAL;
  unsigned short* out = bsign + (size_t)c * K_TOTAL;
  float acc = 0.0f;
#pragma unroll
  for (int j = 0; j < 9; ++j) {
    const int k = t + 256 * j;
    const float v = row[k];
    acc += __builtin_fabsf(v);
    out[k] = (v > 0.0f) ? (unsigned short)0x3F80
           : ((v < 0.0f) ? (unsigned short)0xBF80 : (unsigned short)0);
  }
#pragma unroll
  for (int o = 32; o > 0; o >>= 1) acc += __shfl_down(acc, o, 64);
  __shared__ float red[4];
  if ((t & 63) == 0) red[t >> 6] = acc;
  __syncthreads();
  if (t == 0) scale[c] = (red[0] + red[1] + red[2] + red[3]) * (1.0f / 2304.0f);
}

// ---- main: per WG = 16 m-rows x 256 cout (8 waves x 32c), LDS-staged coalesced NT output ----
__global__ __launch_bounds__(512, 1) void satconv_kernel(
    const float* __restrict__ x, const unsigned short* __restrict__ bsign,
    const float* __restrict__ scale, float* __restrict__ y_out,
    float* __restrict__ psum_out) {
  extern __shared__ char smem[];
  unsigned short* Atile = (unsigned short*)smem;               // [16][KSTRIDE] bf16
  float* stage_base = (float*)(smem + ATILE_BYTES);            // [8 waves][2304] f32

  const int tid = threadIdx.x;
  // XCD swizzle: 8 XCDs x 196 tiles; each XCD owns one batch image (x slice 3.2MB
  // + bsign 1.18MB fit its private 4MB L2).
  const int m_tile = (blockIdx.x & 7) * TILES_PER_IMG + (blockIdx.x >> 3);
  const int m0 = m_tile << 4;

  // ---------- build A tile: lanes 0-15 = consecutive m (= consecutive ow), coalesced x reads ----------
  {
    const int ml = tid & 15;
    const int grp = tid >> 4;                 // 0..31
    const int m = m0 + ml;
    const int b = m / L_SPATIAL;
    const int l = m - b * L_SPATIAL;
    const int oh = l / HW;
    const int ow = l - oh * HW;
    const float* xb = x + (size_t)b * (CIN * L_SPATIAL);
    unsigned short* arow = Atile + ml * KSTRIDE;
    for (int r = grp; r < 768; r += 32) {     // r = ci*3 + kh
      const int ci = r / 3;
      const int kh = r - ci * 3;
      const int h = oh + kh - 1;
      const bool hv = ((unsigned)h < (unsigned)HW);
      const float* xr = xb + (ci * HW + h) * HW;
      const int kb = ci * 9 + kh * 3;
#pragma unroll
      for (int kw = 0; kw < 3; ++kw) {
        const int wv = ow + kw - 1;
        float v = 0.0f;
        if (hv && ((unsigned)wv < (unsigned)HW)) v = xr[wv];
        __hip_bfloat16 bv = __float2bfloat16(v);
        arow[kb + kw] = *reinterpret_cast<unsigned short*>(&bv);
      }
    }
  }

  const int lane = tid & 63;
  const int wave = tid >> 6;                  // 0..7
  const int cl = lane & 15;
  const int q = lane >> 4;
  const int c0 = wave << 5;                   // 32 couts per wave
  float* stage = stage_base + wave * STAGE_FLOATS;   // private -> DS in-order per wave

  // hoist ALL scalar global loads before the store streams (keeps vmcnt clean)
  const float sc_s0 = scale[c0 + cl];
  const float sc_s1 = scale[c0 + 16 + cl];

  // precompute store-phase indices (lane+it dependent only; rg/s added later)
  int base_it[9];
  {
#pragma unroll
    for (int it = 0; it < 9; ++it) {
      const int f = it * 256 + lane * 4;
      const int qq = f / 576;
      const int rem = f - qq * 576;
      const int ci = rem / 36;
      const int n0 = rem - ci * 36;
      base_it[it] = ((m0 + (qq << 2)) * COUT + ci) * NT + n0;
    }
  }

  __syncthreads();

  const unsigned short* aptr = Atile + cl * KSTRIDE + q * 8;
  const int b_img = m0 / L_SPATIAL;           // WG never crosses batch boundary
  const int l0 = m0 - b_img * L_SPATIAL;

  for (int s = 0; s < 2; ++s) {               // 2 c-subtiles of 16 per wave
    const int csub0 = c0 + (s << 4);
    const int c = csub0 + cl;
    const unsigned short* bptr = bsign + (size_t)c * K_TOTAL + q * 8;
    f32x4 ps[NT];
    f32x4 sacc = {0.0f, 0.0f, 0.0f, 0.0f};
    const f32x4 zero = {0.0f, 0.0f, 0.0f, 0.0f};
    bf16x8 b0 = *reinterpret_cast<const bf16x8*>(bptr);
    bf16x8 b1 = *reinterpret_cast<const bf16x8*>(bptr + 32);
#pragma unroll
    for (int n = 0; n < NT; ++n) {
      bf16x8 nb0, nb1;
      if (n + 1 < NT) {                        // prefetch next B-frag
        nb0 = *reinterpret_cast<const bf16x8*>(bptr + (n + 1) * 64);
        nb1 = *reinterpret_cast<const bf16x8*>(bptr + (n + 1) * 64 + 32);
      }
      bf16x8 a0 = *reinterpret_cast<const bf16x8*>(aptr + n * 64);
      bf16x8 a1 = *reinterpret_cast<const bf16x8*>(aptr + n * 64 + 32);
      f32x4 acc = __builtin_amdgcn_mfma_f32_16x16x32_bf16(a0, b0, zero, 0, 0, 0);
      acc = __builtin_amdgcn_mfma_f32_16x16x32_bf16(a1, b1, acc, 0, 0, 0);
      ps[n] = acc;
      if (n == 0) {
        sacc = acc;                           // scan carry starts UNCLIPPED (matches ref)
      } else {
#pragma unroll
        for (int e = 0; e < 4; ++e) {
          const float t = sacc[e] + acc[e];
          sacc[e] = __builtin_amdgcn_fmed3f(t, QMINF, QMAXF);
        }
      }
      b0 = nb0;
      b1 = nb1;
    }

    // ---- y: stage 16c x 16m block, store full 64B lines (NT) ----
    {
      const float sc = (s == 0) ? sc_s0 : sc_s1;
      f32x4 yv;
#pragma unroll
      for (int e = 0; e < 4; ++e) yv[e] = sacc[e] * sc;
      *reinterpret_cast<f32x4*>(stage + cl * 16 + q * 4) = yv;   // [c][m'] layout
      const int ci = lane >> 2;
      const int mi = (lane & 3) << 2;
      f32x4 v = *reinterpret_cast<const f32x4*>(stage + lane * 4);
      nt_store4(y_out + ((size_t)b_img * COUT + (csub0 + ci)) * L_SPATIAL + l0 + mi, v);
    }

    // ---- psum: transpose via per-wave LDS staging, dense 1KB NT wave stores ----
    const int soff = csub0 * NT;              // c-subtile offset in global
#pragma unroll
    for (int rg = 0; rg < 4; ++rg) {
#pragma unroll
      for (int g = 0; g < 9; ++g) {
        f32x4 v = {ps[4 * g + 0][rg], ps[4 * g + 1][rg],
                   ps[4 * g + 2][rg], ps[4 * g + 3][rg]};
        *reinterpret_cast<f32x4*>(stage + q * 576 + cl * 36 + 4 * g) = v;
      }
      const int rgoff = rg * (COUT * NT) + soff;
#pragma unroll
      for (int it = 0; it < 9; ++it) {
        f32x4 v = *reinterpret_cast<const f32x4*>(stage + it * 256 + lane * 4);
        nt_store4(psum_out + (size_t)(base_it[it] + rgoff), v);
      }
    }
  }
}

extern "C" void kernel_launch(void* const* d_in, const int* in_sizes, int n_in,
                              void* d_out, int out_size, void* d_ws, size_t ws_size,
                              hipStream_t stream) {
  const float* x = (const float*)d_in[0];
  const float* w = (const float*)d_in[1];
  float* y = (float*)d_out;
  float* psum = y + (size_t)BATCH * COUT * L_SPATIAL;            // y is 6,422,528 floats
  unsigned short* bsign = (unsigned short*)d_ws;                 // 256*2304*2 = 1,179,648 B
  float* scale = (float*)((char*)d_ws + (size_t)COUT * K_TOTAL * 2);

  prep_kernel<<<COUT, 256, 0, stream>>>(w, bsign, scale);

  hipFuncSetAttribute(reinterpret_cast<const void*>(satconv_kernel),
                      hipFuncAttributeMaxDynamicSharedMemorySize, LDS_BYTES);
  satconv_kernel<<<(BATCH * L_SPATIAL) / 16, 512, LDS_BYTES, stream>>>(
      x, bsign, scale, y, psum);
}